// Round 11
// baseline (170.963 us; speedup 1.0000x reference)
//
#include <hip/hip_runtime.h>
#include <hip/hip_bf16.h>
#include <hip/hip_fp16.h>
#include <math.h>

#define N_NODES   100000
#define N_EDGES   1600000
#define D_FEAT    128
#define N_CLASSES 64

#define BKT_SHIFT 7                     // 128 nodes per bucket
#define BKT_NODES 128
#define NB        782                   // ceil(100000/128)
#define CAP       2560                  // per-bucket capacity (avg 2048)
#define CHUNK     8192                  // edges per bin block
#define NBLK_A    ((N_EDGES + CHUNK - 1) / CHUNK)   // 196
#define GROWS     128                   // rows per gemm block == one bucket
#define NBLK_G    NB                    // 782

#define BSTRIDE   16                    // bcnt padded: 1 counter / 64B line
                                        // (196 blocks x 782 atomicAdds were
                                        //  16-per-line -> ~3100 serialized
                                        //  RMWs/line across 8 XCDs)

// ws layout (max extent 21,212,160 B):
//   bcnt   @ 0          (50,048 B padded: NB x 16 ints)
//   binned @ 404,480    (8,007,680 B)
//   zp     @ 8,412,160  (12,800,000 B, fp16)
#define OFF_BINNED 404480
#define OFF_ZP     8412160

typedef __attribute__((ext_vector_type(8))) short bf16x8;
typedef __attribute__((ext_vector_type(4))) float f32x4;
typedef __attribute__((ext_vector_type(4))) unsigned int u32x4;

static __device__ inline unsigned f2bf1(float f) {
    unsigned u = __float_as_uint(f);
    return (u + 0x7FFF + ((u >> 16) & 1)) >> 16;     // RNE
}
static __device__ inline unsigned pack2(float a, float b) {
    return f2bf1(a) | (f2bf1(b) << 16);
}
static __device__ inline float2 h2f2(unsigned u) {
    __half2 h = *(__half2*)&u;
    return __half22float2(h);
}
static __device__ inline unsigned hadd2u(unsigned a, unsigned b) {
    __half2 ha = *(__half2*)&a;
    __half2 hb = *(__half2*)&b;
    __half2 r  = __hadd2(ha, hb);
    return *(unsigned*)&r;
}

// ---------------------------------------------------------------------------
// K1: bin edges into NB coarse buckets; LDS bucket-sort, coalesced run writes.
//     (round-6 form; bcnt now cacheline-padded)
// ---------------------------------------------------------------------------
__global__ __launch_bounds__(1024) void bin_kernel(const int* __restrict__ src,
                                                   const int* __restrict__ dst,
                                                   int* __restrict__ bcnt,
                                                   int* __restrict__ binned) {
    __shared__ int hist[NB];                   // counts, then scatter cursor
    __shared__ int rbase[NB];                  // global run base (via bcnt)
    __shared__ int loc[NB];                    // exclusive prefix within block
    __shared__ int wsum[16];
    __shared__ int dbuf[CHUNK];                // staged dst (32 KB)
    __shared__ int sbuf[CHUNK];                // bucket-sorted packed (32 KB)

    const int tid  = threadIdx.x;
    const int lane = tid & 63;
    const int wid  = tid >> 6;
    const int e0 = blockIdx.x * CHUNK;
    const int e1 = min(e0 + CHUNK, N_EDGES);
    const int n  = e1 - e0;

    if (tid < NB) hist[tid] = 0;
    __syncthreads();

    // pass 1: stage dst + histogram
    for (int i = tid; i < n; i += 1024) {
        int d = dst[e0 + i];
        dbuf[i] = d;
        atomicAdd(&hist[d >> BKT_SHIFT], 1);
    }
    __syncthreads();

    // pass 2: block-wide exclusive scan of hist -> loc; reserve global runs
    int x = (tid < NB) ? hist[tid] : 0;
    int sc = x;
#pragma unroll
    for (int off = 1; off < 64; off <<= 1) {
        int t = __shfl_up(sc, off, 64);
        if (lane >= off) sc += t;
    }
    if (lane == 63) wsum[wid] = sc;
    __syncthreads();
    if (tid < 16) {
        int w  = wsum[tid];
        int ws = w;
#pragma unroll
        for (int off = 1; off < 16; off <<= 1) {
            int t = __shfl_up(ws, off, 16);
            if (tid >= off) ws += t;
        }
        wsum[tid] = ws - w;                    // exclusive wave offset
    }
    __syncthreads();
    if (tid < NB) {
        loc[tid] = sc - x + wsum[wid];         // exclusive prefix
        if (x) rbase[tid] = atomicAdd(&bcnt[tid * BSTRIDE], x);
        hist[tid] = 0;                         // reuse as scatter cursor
    }
    __syncthreads();

    // pass 3: scatter into bucket-sorted LDS order
    for (int i = tid; i < n; i += 1024) {
        int d   = dbuf[i];
        int sv  = src[e0 + i];
        int bkt = d >> BKT_SHIFT;
        int p   = atomicAdd(&hist[bkt], 1);
        sbuf[loc[bkt] + p] = (sv << BKT_SHIFT) | (d & (BKT_NODES - 1));
    }
    __syncthreads();

    // pass 4: write runs out coalesced (16-lane group per bucket run)
    const int g16 = lane >> 4;                 // 0..3
    const int l16 = lane & 15;
    for (int b2 = wid * 4 + g16; b2 < NB; b2 += 64) {
        const int len = hist[b2];
        if (!len) continue;
        const int st = loc[b2];
        const int rb = rbase[b2];
        for (int k = l16; k < len; k += 16) {
            const int off = rb + k;
            if (off < CAP)                     // memory guard
                binned[b2 * CAP + off] = sbuf[st + k];
        }
    }
}

// ---------------------------------------------------------------------------
// K2: zp[i][c] = rsqrt(indeg[i]+1) * (x @ W^T)[i][c]  via bf16 MFMA.
//     Block b == bucket b; per-node degree from an LDS histogram of the
//     bucket's binned run (overlaps W staging). (round-10 form, proven)
// ---------------------------------------------------------------------------
__global__ __launch_bounds__(256) void gemm_kernel(const float* __restrict__ x,
                                                   const float* __restrict__ W,
                                                   const int* __restrict__ bcnt,
                                                   const int* __restrict__ binned,
                                                   __half* __restrict__ zp) {
    __shared__ short Wb[64 * 136];
    __shared__ int hcnt[BKT_NODES];
    const int tid  = threadIdx.x;

    if (tid < BKT_NODES) hcnt[tid] = 0;
    __syncthreads();

    // W staging + bucket degree histogram (same phase, independent work)
    const float4* __restrict__ W4 = (const float4*)W;
    for (int idx = tid; idx < 64 * 32; idx += 256) {
        int nn = idx >> 5, k4 = idx & 31;
        float4 v = W4[idx];
        uint2 p;
        p.x = pack2(v.x, v.y);
        p.y = pack2(v.z, v.w);
        *(uint2*)&Wb[nn * 136 + k4 * 4] = p;
    }
    {
        const int n    = min(bcnt[blockIdx.x * BSTRIDE], CAP);
        const int base = blockIdx.x * CAP;
        for (int i = tid; i < n; i += 256)
            atomicAdd(&hcnt[binned[base + i] & (BKT_NODES - 1)], 1);
    }
    __syncthreads();

    const int lane = tid & 63;
    const int wv   = tid >> 6;
    const int m    = lane & 15;
    const int half = lane >> 4;

    bf16x8 bfr[4][4];
#pragma unroll
    for (int t = 0; t < 4; t++)
#pragma unroll
        for (int j = 0; j < 4; j++)
            bfr[t][j] = *(bf16x8*)&Wb[(j * 16 + m) * 136 + t * 32 + half * 8];

#pragma unroll
    for (int rt = 0; rt < 2; rt++) {
        const int row0 = blockIdx.x * GROWS + rt * 64;
        const int arow = min(row0 + wv * 16 + m, N_NODES - 1);
        const float4* __restrict__ xr = (const float4*)&x[arow * D_FEAT];

        f32x4 acc[4];
#pragma unroll
        for (int j = 0; j < 4; j++) acc[j] = (f32x4){0.f, 0.f, 0.f, 0.f};

#pragma unroll
        for (int t = 0; t < 4; t++) {
            const float4 p0 = xr[t * 8 + half * 2];
            const float4 p1 = xr[t * 8 + half * 2 + 1];
            union { bf16x8 v; unsigned u[4]; } au;
            au.u[0] = pack2(p0.x, p0.y);
            au.u[1] = pack2(p0.z, p0.w);
            au.u[2] = pack2(p1.x, p1.y);
            au.u[3] = pack2(p1.z, p1.w);
#pragma unroll
            for (int j = 0; j < 4; j++)
                acc[j] = __builtin_amdgcn_mfma_f32_16x16x32_bf16(au.v, bfr[t][j], acc[j], 0, 0, 0);
        }

#pragma unroll
        for (int r = 0; r < 4; r++) {
            const int row = row0 + wv * 16 + half * 4 + r;
            if (row < N_NODES) {
                const int nl = rt * 64 + wv * 16 + half * 4 + r;   // 0..127
                const float dinv = rsqrtf((float)(hcnt[nl] + 1));
#pragma unroll
                for (int j = 0; j < 4; j++)
                    zp[row * N_CLASSES + j * 16 + m] = __float2half(acc[j][r] * dinv);
            }
        }
    }
}

// ---------------------------------------------------------------------------
// K3: fused sort + gather-accumulate + epilogue. (round-8 v4 form, proven)
// ---------------------------------------------------------------------------
__global__ __launch_bounds__(1024) void agg_kernel(const int* __restrict__ bcnt,
                                                   const int* __restrict__ binned,
                                                   const __half* __restrict__ zp,
                                                   const float* __restrict__ b,
                                                   float* __restrict__ out) {
    __shared__ int buf[CAP];
    __shared__ int sorted[CAP];
    __shared__ int hcnt[BKT_NODES];
    __shared__ int cur[BKT_NODES];
    __shared__ int rowstart[BKT_NODES];

    const int tid  = threadIdx.x;
    const int lane = tid & 63;
    const int wid  = tid >> 6;                 // 0..15

    if (tid < BKT_NODES) { hcnt[tid] = 0; cur[tid] = 0; }
    __syncthreads();

    const int bkt  = blockIdx.x;
    const int n    = min(bcnt[bkt * BSTRIDE], CAP);
    const int base = bkt * CAP;

    for (int i = tid; i < n; i += 1024) {
        int v = binned[base + i];
        buf[i] = v;
        atomicAdd(&hcnt[v & (BKT_NODES - 1)], 1);
    }
    __syncthreads();

    if (wid == 0) {
        int v0 = hcnt[lane];
        int v1 = hcnt[64 + lane];
        int s0 = v0;
#pragma unroll
        for (int off = 1; off < 64; off <<= 1) {
            int t = __shfl_up(s0, off, 64);
            if (lane >= off) s0 += t;
        }
        int tot0 = __shfl(s0, 63, 64);
        int s1 = v1;
#pragma unroll
        for (int off = 1; off < 64; off <<= 1) {
            int t = __shfl_up(s1, off, 64);
            if (lane >= off) s1 += t;
        }
        rowstart[lane]      = s0 - v0;             // exclusive
        rowstart[64 + lane] = s1 + tot0 - v1;
    }
    __syncthreads();

    for (int i = tid; i < n; i += 1024) {
        int v  = buf[i];
        int nd = v & (BKT_NODES - 1);
        int p  = atomicAdd(&cur[nd], 1);
        sorted[rowstart[nd] + p] = v >> BKT_SHIFT;
    }
    __syncthreads();

    // gather phase: 16 waves x 2 nodes/wave x 4 passes = 128 nodes
    const int half = lane >> 5;                 // 0 = node A, 1 = node B
    const int sub  = (lane >> 3) & 3;           // edge slot 0..3 within node
    const int o8   = (lane & 7) * 8;            // class octet start

#pragma unroll 1
    for (int pass = 0; pass < 4; pass++) {
        const int nl   = pass * 32 + wid * 2 + half;
        const int node = bkt * BKT_NODES + nl;
        const int cnt  = hcnt[nl];
        const int st   = rowstart[nl];

        float a8[8] = {0.f, 0.f, 0.f, 0.f, 0.f, 0.f, 0.f, 0.f};
        for (int be = 0; be < cnt; be += 64) {
            const int en = min(cnt - be, 64);
            unsigned p2[4] = {0u, 0u, 0u, 0u};
            for (int e = sub; e < en; e += 4) {
                const int row = sorted[st + be + e];
                const u32x4 g = *(const u32x4*)&zp[row * N_CLASSES + o8];
#pragma unroll
                for (int k = 0; k < 4; k++) p2[k] = hadd2u(p2[k], g[k]);
            }
#pragma unroll
            for (int k = 0; k < 4; k++) {
                float2 f = h2f2(p2[k]);
                a8[2 * k]     += f.x;
                a8[2 * k + 1] += f.y;
            }
        }
        // combine 4 edge slots (xor 8,16 — stays within each 32-lane half)
#pragma unroll
        for (int mask = 8; mask <= 16; mask <<= 1)
#pragma unroll
            for (int k = 0; k < 8; k++)
                a8[k] += __shfl_xor(a8[k], mask, 64);

        if (node < N_NODES) {
            // self-loop
            const u32x4 sg = *(const u32x4*)&zp[node * N_CLASSES + o8];
#pragma unroll
            for (int k = 0; k < 4; k++) {
                float2 f = h2f2(sg[k]);
                a8[2 * k]     += f.x;
                a8[2 * k + 1] += f.y;
            }

            const float dinv = rsqrtf((float)(cnt + 1));
            float v[8];
#pragma unroll
            for (int k = 0; k < 8; k++) v[k] = a8[k] * dinv + b[o8 + k];

            float m = v[0];
#pragma unroll
            for (int k = 1; k < 8; k++) m = fmaxf(m, v[k]);
#pragma unroll
            for (int mask = 1; mask <= 4; mask <<= 1)
                m = fmaxf(m, __shfl_xor(m, mask, 64));
            float l = 0.f;
#pragma unroll
            for (int k = 0; k < 8; k++) l += __expf(v[k] - m);
#pragma unroll
            for (int mask = 1; mask <= 4; mask <<= 1)
                l += __shfl_xor(l, mask, 64);
            const float lg = m + __logf(l);

            if (sub == 0) {
                float4 o0, o1;
                o0.x = v[0] - lg; o0.y = v[1] - lg; o0.z = v[2] - lg; o0.w = v[3] - lg;
                o1.x = v[4] - lg; o1.y = v[5] - lg; o1.z = v[6] - lg; o1.w = v[7] - lg;
                *(float4*)&out[node * N_CLASSES + o8]     = o0;
                *(float4*)&out[node * N_CLASSES + o8 + 4] = o1;
            }
        }
    }
}

// ---------------------------------------------------------------------------
// Launch
// ---------------------------------------------------------------------------
extern "C" void kernel_launch(void* const* d_in, const int* in_sizes, int n_in,
                              void* d_out, int out_size, void* d_ws, size_t ws_size,
                              hipStream_t stream) {
    const float* x    = (const float*)d_in[0];
    const int*   edge = (const int*)d_in[1];   // [2,E]: src then dst
    const float* W    = (const float*)d_in[2];
    const float* b    = (const float*)d_in[3];
    float* out = (float*)d_out;

    char* ws = (char*)d_ws;
    int*    bcnt   = (int*)(ws);               // padded: NB x BSTRIDE ints
    int*    binned = (int*)(ws + OFF_BINNED);
    __half* zp     = (__half*)(ws + OFF_ZP);

    const int* srcv = edge;
    const int* dstv = edge + N_EDGES;

    hipMemsetAsync(bcnt, 0, NB * BSTRIDE * sizeof(int), stream);
    bin_kernel<<<NBLK_A, 1024, 0, stream>>>(srcv, dstv, bcnt, binned);
    gemm_kernel<<<NBLK_G, 256, 0, stream>>>(x, W, bcnt, binned, zp);
    agg_kernel<<<NB, 1024, 0, stream>>>(bcnt, binned, zp, b, out);
}

// Round 12
// 168.986 us; speedup vs baseline: 1.0117x; 1.0117x over previous
//
#include <hip/hip_runtime.h>
#include <hip/hip_bf16.h>
#include <hip/hip_fp16.h>
#include <math.h>

#define N_NODES   100000
#define N_EDGES   1600000
#define D_FEAT    128
#define N_CLASSES 64

#define BKT_SHIFT 7                     // 128 nodes per bucket
#define BKT_NODES 128
#define NB        782                   // ceil(100000/128)
#define CAP       2560                  // per-bucket capacity (avg 2048)
#define CHUNK     8192                  // edges per bin block
#define NBLK_A    ((N_EDGES + CHUNK - 1) / CHUNK)   // 196
#define GROWS     128                   // rows per gemm block == one bucket
#define NBLK_G    NB                    // 782

// ws layout (max extent 21,212,160 B):
//   (spare) @ 0          (400,000 B)
//   bcnt   @ 400,384    (3,128 B)
//   binned @ 404,480    (8,007,680 B)
//   zp     @ 8,412,160  (12,800,000 B, fp16)
#define OFF_BCNT   400384
#define OFF_BINNED 404480
#define OFF_ZP     8412160

typedef __attribute__((ext_vector_type(8))) short bf16x8;
typedef __attribute__((ext_vector_type(4))) float f32x4;
typedef __attribute__((ext_vector_type(4))) unsigned int u32x4;

static __device__ inline unsigned f2bf1(float f) {
    unsigned u = __float_as_uint(f);
    return (u + 0x7FFF + ((u >> 16) & 1)) >> 16;     // RNE
}
static __device__ inline unsigned pack2(float a, float b) {
    return f2bf1(a) | (f2bf1(b) << 16);
}
static __device__ inline float2 h2f2(unsigned u) {
    __half2 h = *(__half2*)&u;
    return __half22float2(h);
}
static __device__ inline unsigned hadd2u(unsigned a, unsigned b) {
    __half2 ha = *(__half2*)&a;
    __half2 hb = *(__half2*)&b;
    __half2 r  = __hadd2(ha, hb);
    return *(unsigned*)&r;
}

// ---------------------------------------------------------------------------
// K1: bin edges into NB coarse buckets; LDS bucket-sort, coalesced run writes.
//     v3: pass-4 is a dense thread-per-element write using the closed-form
//     output position off = rbase[bkt] + (i - loc[bkt]) — no per-run loop,
//     no idle lanes (old 16-lane-group writer idled ~40% on ~10-edge runs).
//     Element buckets recorded during pass-3 scatter (dbuf reused after a
//     register stage).
// ---------------------------------------------------------------------------
__global__ __launch_bounds__(1024) void bin_kernel(const int* __restrict__ src,
                                                   const int* __restrict__ dst,
                                                   int* __restrict__ bcnt,
                                                   int* __restrict__ binned) {
    __shared__ int hist[NB];                   // counts, then scatter cursor
    __shared__ int rbase[NB];                  // global run base (via bcnt)
    __shared__ int loc[NB];                    // exclusive prefix within block
    __shared__ int wsum[16];
    __shared__ int dbuf[CHUNK];                // staged dst, then element bkt
    __shared__ int sbuf[CHUNK];                // bucket-sorted packed (32 KB)

    const int tid  = threadIdx.x;
    const int lane = tid & 63;
    const int wid  = tid >> 6;
    const int e0 = blockIdx.x * CHUNK;
    const int e1 = min(e0 + CHUNK, N_EDGES);
    const int n  = e1 - e0;

    if (tid < NB) hist[tid] = 0;
    __syncthreads();

    // pass 1: stage dst + histogram
    for (int i = tid; i < n; i += 1024) {
        int d = dst[e0 + i];
        dbuf[i] = d;
        atomicAdd(&hist[d >> BKT_SHIFT], 1);
    }
    __syncthreads();

    // pass 2: block-wide exclusive scan of hist -> loc; reserve global runs
    int x = (tid < NB) ? hist[tid] : 0;
    int sc = x;
#pragma unroll
    for (int off = 1; off < 64; off <<= 1) {
        int t = __shfl_up(sc, off, 64);
        if (lane >= off) sc += t;
    }
    if (lane == 63) wsum[wid] = sc;
    __syncthreads();
    if (tid < 16) {
        int w  = wsum[tid];
        int ws = w;
#pragma unroll
        for (int off = 1; off < 16; off <<= 1) {
            int t = __shfl_up(ws, off, 16);
            if (tid >= off) ws += t;
        }
        wsum[tid] = ws - w;                    // exclusive wave offset
    }
    __syncthreads();
    if (tid < NB) {
        loc[tid] = sc - x + wsum[wid];         // exclusive prefix
        if (x) rbase[tid] = atomicAdd(&bcnt[tid], x);
        hist[tid] = 0;                         // reuse as scatter cursor
    }
    __syncthreads();

    // pass 3a: pull this thread's dst + src elements into registers
    int rd[8], rs[8];
    int cnt = 0;
    for (int i = tid; i < n; i += 1024) {
        rd[cnt] = dbuf[i];
        rs[cnt] = src[e0 + i];
        cnt++;
    }
    __syncthreads();                           // all dbuf reads done

    // pass 3b: scatter into bucket-sorted LDS order; record element bucket
    for (int j = 0; j < cnt; j++) {
        int d   = rd[j];
        int bkt = d >> BKT_SHIFT;
        int p   = atomicAdd(&hist[bkt], 1);
        int q   = loc[bkt] + p;
        sbuf[q] = (rs[j] << BKT_SHIFT) | (d & (BKT_NODES - 1));
        dbuf[q] = bkt;
    }
    __syncthreads();

    // pass 4: dense coalesced write-out (closed-form position)
    for (int i = tid; i < n; i += 1024) {
        const int bkt = dbuf[i];
        const int off = rbase[bkt] + (i - loc[bkt]);
        if (off < CAP)                         // memory guard
            binned[bkt * CAP + off] = sbuf[i];
    }
}

// ---------------------------------------------------------------------------
// K2: zp[i][c] = rsqrt(indeg[i]+1) * (x @ W^T)[i][c]  via bf16 MFMA.
//     Block b == bucket b; per-node degree from an LDS histogram of the
//     bucket's binned run (overlaps W staging). (round-10 form, proven)
// ---------------------------------------------------------------------------
__global__ __launch_bounds__(256) void gemm_kernel(const float* __restrict__ x,
                                                   const float* __restrict__ W,
                                                   const int* __restrict__ bcnt,
                                                   const int* __restrict__ binned,
                                                   __half* __restrict__ zp) {
    __shared__ short Wb[64 * 136];
    __shared__ int hcnt[BKT_NODES];
    const int tid  = threadIdx.x;

    if (tid < BKT_NODES) hcnt[tid] = 0;
    __syncthreads();

    // W staging + bucket degree histogram (same phase, independent work)
    const float4* __restrict__ W4 = (const float4*)W;
    for (int idx = tid; idx < 64 * 32; idx += 256) {
        int nn = idx >> 5, k4 = idx & 31;
        float4 v = W4[idx];
        uint2 p;
        p.x = pack2(v.x, v.y);
        p.y = pack2(v.z, v.w);
        *(uint2*)&Wb[nn * 136 + k4 * 4] = p;
    }
    {
        const int n    = min(bcnt[blockIdx.x], CAP);
        const int base = blockIdx.x * CAP;
        for (int i = tid; i < n; i += 256)
            atomicAdd(&hcnt[binned[base + i] & (BKT_NODES - 1)], 1);
    }
    __syncthreads();

    const int lane = tid & 63;
    const int wv   = tid >> 6;
    const int m    = lane & 15;
    const int half = lane >> 4;

    bf16x8 bfr[4][4];
#pragma unroll
    for (int t = 0; t < 4; t++)
#pragma unroll
        for (int j = 0; j < 4; j++)
            bfr[t][j] = *(bf16x8*)&Wb[(j * 16 + m) * 136 + t * 32 + half * 8];

#pragma unroll
    for (int rt = 0; rt < 2; rt++) {
        const int row0 = blockIdx.x * GROWS + rt * 64;
        const int arow = min(row0 + wv * 16 + m, N_NODES - 1);
        const float4* __restrict__ xr = (const float4*)&x[arow * D_FEAT];

        f32x4 acc[4];
#pragma unroll
        for (int j = 0; j < 4; j++) acc[j] = (f32x4){0.f, 0.f, 0.f, 0.f};

#pragma unroll
        for (int t = 0; t < 4; t++) {
            const float4 p0 = xr[t * 8 + half * 2];
            const float4 p1 = xr[t * 8 + half * 2 + 1];
            union { bf16x8 v; unsigned u[4]; } au;
            au.u[0] = pack2(p0.x, p0.y);
            au.u[1] = pack2(p0.z, p0.w);
            au.u[2] = pack2(p1.x, p1.y);
            au.u[3] = pack2(p1.z, p1.w);
#pragma unroll
            for (int j = 0; j < 4; j++)
                acc[j] = __builtin_amdgcn_mfma_f32_16x16x32_bf16(au.v, bfr[t][j], acc[j], 0, 0, 0);
        }

#pragma unroll
        for (int r = 0; r < 4; r++) {
            const int row = row0 + wv * 16 + half * 4 + r;
            if (row < N_NODES) {
                const int nl = rt * 64 + wv * 16 + half * 4 + r;   // 0..127
                const float dinv = rsqrtf((float)(hcnt[nl] + 1));
#pragma unroll
                for (int j = 0; j < 4; j++)
                    zp[row * N_CLASSES + j * 16 + m] = __float2half(acc[j][r] * dinv);
            }
        }
    }
}

// ---------------------------------------------------------------------------
// K3: fused sort + gather-accumulate + epilogue. (round-8 v4 form, proven)
// ---------------------------------------------------------------------------
__global__ __launch_bounds__(1024) void agg_kernel(const int* __restrict__ bcnt,
                                                   const int* __restrict__ binned,
                                                   const __half* __restrict__ zp,
                                                   const float* __restrict__ b,
                                                   float* __restrict__ out) {
    __shared__ int buf[CAP];
    __shared__ int sorted[CAP];
    __shared__ int hcnt[BKT_NODES];
    __shared__ int cur[BKT_NODES];
    __shared__ int rowstart[BKT_NODES];

    const int tid  = threadIdx.x;
    const int lane = tid & 63;
    const int wid  = tid >> 6;                 // 0..15

    if (tid < BKT_NODES) { hcnt[tid] = 0; cur[tid] = 0; }
    __syncthreads();

    const int bkt  = blockIdx.x;
    const int n    = min(bcnt[bkt], CAP);
    const int base = bkt * CAP;

    for (int i = tid; i < n; i += 1024) {
        int v = binned[base + i];
        buf[i] = v;
        atomicAdd(&hcnt[v & (BKT_NODES - 1)], 1);
    }
    __syncthreads();

    if (wid == 0) {
        int v0 = hcnt[lane];
        int v1 = hcnt[64 + lane];
        int s0 = v0;
#pragma unroll
        for (int off = 1; off < 64; off <<= 1) {
            int t = __shfl_up(s0, off, 64);
            if (lane >= off) s0 += t;
        }
        int tot0 = __shfl(s0, 63, 64);
        int s1 = v1;
#pragma unroll
        for (int off = 1; off < 64; off <<= 1) {
            int t = __shfl_up(s1, off, 64);
            if (lane >= off) s1 += t;
        }
        rowstart[lane]      = s0 - v0;             // exclusive
        rowstart[64 + lane] = s1 + tot0 - v1;
    }
    __syncthreads();

    for (int i = tid; i < n; i += 1024) {
        int v  = buf[i];
        int nd = v & (BKT_NODES - 1);
        int p  = atomicAdd(&cur[nd], 1);
        sorted[rowstart[nd] + p] = v >> BKT_SHIFT;
    }
    __syncthreads();

    // gather phase: 16 waves x 2 nodes/wave x 4 passes = 128 nodes
    const int half = lane >> 5;                 // 0 = node A, 1 = node B
    const int sub  = (lane >> 3) & 3;           // edge slot 0..3 within node
    const int o8   = (lane & 7) * 8;            // class octet start

#pragma unroll 1
    for (int pass = 0; pass < 4; pass++) {
        const int nl   = pass * 32 + wid * 2 + half;
        const int node = bkt * BKT_NODES + nl;
        const int cnt  = hcnt[nl];
        const int st   = rowstart[nl];

        float a8[8] = {0.f, 0.f, 0.f, 0.f, 0.f, 0.f, 0.f, 0.f};
        for (int be = 0; be < cnt; be += 64) {
            const int en = min(cnt - be, 64);
            unsigned p2[4] = {0u, 0u, 0u, 0u};
            for (int e = sub; e < en; e += 4) {
                const int row = sorted[st + be + e];
                const u32x4 g = *(const u32x4*)&zp[row * N_CLASSES + o8];
#pragma unroll
                for (int k = 0; k < 4; k++) p2[k] = hadd2u(p2[k], g[k]);
            }
#pragma unroll
            for (int k = 0; k < 4; k++) {
                float2 f = h2f2(p2[k]);
                a8[2 * k]     += f.x;
                a8[2 * k + 1] += f.y;
            }
        }
        // combine 4 edge slots (xor 8,16 — stays within each 32-lane half)
#pragma unroll
        for (int mask = 8; mask <= 16; mask <<= 1)
#pragma unroll
            for (int k = 0; k < 8; k++)
                a8[k] += __shfl_xor(a8[k], mask, 64);

        if (node < N_NODES) {
            // self-loop
            const u32x4 sg = *(const u32x4*)&zp[node * N_CLASSES + o8];
#pragma unroll
            for (int k = 0; k < 4; k++) {
                float2 f = h2f2(sg[k]);
                a8[2 * k]     += f.x;
                a8[2 * k + 1] += f.y;
            }

            const float dinv = rsqrtf((float)(cnt + 1));
            float v[8];
#pragma unroll
            for (int k = 0; k < 8; k++) v[k] = a8[k] * dinv + b[o8 + k];

            float m = v[0];
#pragma unroll
            for (int k = 1; k < 8; k++) m = fmaxf(m, v[k]);
#pragma unroll
            for (int mask = 1; mask <= 4; mask <<= 1)
                m = fmaxf(m, __shfl_xor(m, mask, 64));
            float l = 0.f;
#pragma unroll
            for (int k = 0; k < 8; k++) l += __expf(v[k] - m);
#pragma unroll
            for (int mask = 1; mask <= 4; mask <<= 1)
                l += __shfl_xor(l, mask, 64);
            const float lg = m + __logf(l);

            if (sub == 0) {
                float4 o0, o1;
                o0.x = v[0] - lg; o0.y = v[1] - lg; o0.z = v[2] - lg; o0.w = v[3] - lg;
                o1.x = v[4] - lg; o1.y = v[5] - lg; o1.z = v[6] - lg; o1.w = v[7] - lg;
                *(float4*)&out[node * N_CLASSES + o8]     = o0;
                *(float4*)&out[node * N_CLASSES + o8 + 4] = o1;
            }
        }
    }
}

// ---------------------------------------------------------------------------
// Launch
// ---------------------------------------------------------------------------
extern "C" void kernel_launch(void* const* d_in, const int* in_sizes, int n_in,
                              void* d_out, int out_size, void* d_ws, size_t ws_size,
                              hipStream_t stream) {
    const float* x    = (const float*)d_in[0];
    const int*   edge = (const int*)d_in[1];   // [2,E]: src then dst
    const float* W    = (const float*)d_in[2];
    const float* b    = (const float*)d_in[3];
    float* out = (float*)d_out;

    char* ws = (char*)d_ws;
    int*    bcnt   = (int*)(ws + OFF_BCNT);
    int*    binned = (int*)(ws + OFF_BINNED);
    __half* zp     = (__half*)(ws + OFF_ZP);

    const int* srcv = edge;
    const int* dstv = edge + N_EDGES;

    hipMemsetAsync(bcnt, 0, NB * sizeof(int), stream);
    bin_kernel<<<NBLK_A, 1024, 0, stream>>>(srcv, dstv, bcnt, binned);
    gemm_kernel<<<NBLK_G, 256, 0, stream>>>(x, W, bcnt, binned, zp);
    agg_kernel<<<NB, 1024, 0, stream>>>(bcnt, binned, zp, b, out);
}

// Round 13
// 165.912 us; speedup vs baseline: 1.0304x; 1.0185x over previous
//
#include <hip/hip_runtime.h>
#include <hip/hip_bf16.h>
#include <hip/hip_fp16.h>
#include <math.h>

#define N_NODES   100000
#define N_EDGES   1600000
#define D_FEAT    128
#define N_CLASSES 64

#define BKT_SHIFT 7                     // 128 nodes per bucket
#define BKT_NODES 128
#define NB        782                   // ceil(100000/128)
#define CAP       2560                  // per-bucket capacity (avg 2048)
#define CHUNK     8192                  // edges per bin block
#define NBLK_A    ((N_EDGES + CHUNK - 1) / CHUNK)   // 196
#define GROWS     128                   // rows per gemm block == one bucket
#define NBLK_G    NB                    // 782

// ws layout (max extent 21,212,160 B):
//   (spare) @ 0          (400,000 B)
//   bcnt   @ 400,384    (3,128 B)
//   binned @ 404,480    (8,007,680 B)
//   zp     @ 8,412,160  (12,800,000 B, fp16)
#define OFF_BCNT   400384
#define OFF_BINNED 404480
#define OFF_ZP     8412160

typedef __attribute__((ext_vector_type(8))) short bf16x8;
typedef __attribute__((ext_vector_type(4))) float f32x4;
typedef __attribute__((ext_vector_type(4))) unsigned int u32x4;

static __device__ inline unsigned f2bf1(float f) {
    unsigned u = __float_as_uint(f);
    return (u + 0x7FFF + ((u >> 16) & 1)) >> 16;     // RNE
}
static __device__ inline unsigned pack2(float a, float b) {
    return f2bf1(a) | (f2bf1(b) << 16);
}
static __device__ inline float2 h2f2(unsigned u) {
    __half2 h = *(__half2*)&u;
    return __half22float2(h);
}
static __device__ inline unsigned hadd2u(unsigned a, unsigned b) {
    __half2 ha = *(__half2*)&a;
    __half2 hb = *(__half2*)&b;
    __half2 r  = __hadd2(ha, hb);
    return *(unsigned*)&r;
}

// ---------------------------------------------------------------------------
// K1: bin edges into NB coarse buckets; LDS bucket-sort, dense closed-form
//     coalesced write-out. (round-12 form, proven)
// ---------------------------------------------------------------------------
__global__ __launch_bounds__(1024) void bin_kernel(const int* __restrict__ src,
                                                   const int* __restrict__ dst,
                                                   int* __restrict__ bcnt,
                                                   int* __restrict__ binned) {
    __shared__ int hist[NB];                   // counts, then scatter cursor
    __shared__ int rbase[NB];                  // global run base (via bcnt)
    __shared__ int loc[NB];                    // exclusive prefix within block
    __shared__ int wsum[16];
    __shared__ int dbuf[CHUNK];                // staged dst, then element bkt
    __shared__ int sbuf[CHUNK];                // bucket-sorted packed (32 KB)

    const int tid  = threadIdx.x;
    const int lane = tid & 63;
    const int wid  = tid >> 6;
    const int e0 = blockIdx.x * CHUNK;
    const int e1 = min(e0 + CHUNK, N_EDGES);
    const int n  = e1 - e0;

    if (tid < NB) hist[tid] = 0;
    __syncthreads();

    // pass 1: stage dst + histogram
    for (int i = tid; i < n; i += 1024) {
        int d = dst[e0 + i];
        dbuf[i] = d;
        atomicAdd(&hist[d >> BKT_SHIFT], 1);
    }
    __syncthreads();

    // pass 2: block-wide exclusive scan of hist -> loc; reserve global runs
    int x = (tid < NB) ? hist[tid] : 0;
    int sc = x;
#pragma unroll
    for (int off = 1; off < 64; off <<= 1) {
        int t = __shfl_up(sc, off, 64);
        if (lane >= off) sc += t;
    }
    if (lane == 63) wsum[wid] = sc;
    __syncthreads();
    if (tid < 16) {
        int w  = wsum[tid];
        int ws = w;
#pragma unroll
        for (int off = 1; off < 16; off <<= 1) {
            int t = __shfl_up(ws, off, 16);
            if (tid >= off) ws += t;
        }
        wsum[tid] = ws - w;                    // exclusive wave offset
    }
    __syncthreads();
    if (tid < NB) {
        loc[tid] = sc - x + wsum[wid];         // exclusive prefix
        if (x) rbase[tid] = atomicAdd(&bcnt[tid], x);
        hist[tid] = 0;                         // reuse as scatter cursor
    }
    __syncthreads();

    // pass 3a: pull this thread's dst + src elements into registers
    int rd[8], rs[8];
    int cnt = 0;
    for (int i = tid; i < n; i += 1024) {
        rd[cnt] = dbuf[i];
        rs[cnt] = src[e0 + i];
        cnt++;
    }
    __syncthreads();                           // all dbuf reads done

    // pass 3b: scatter into bucket-sorted LDS order; record element bucket
    for (int j = 0; j < cnt; j++) {
        int d   = rd[j];
        int bkt = d >> BKT_SHIFT;
        int p   = atomicAdd(&hist[bkt], 1);
        int q   = loc[bkt] + p;
        sbuf[q] = (rs[j] << BKT_SHIFT) | (d & (BKT_NODES - 1));
        dbuf[q] = bkt;
    }
    __syncthreads();

    // pass 4: dense coalesced write-out (closed-form position)
    for (int i = tid; i < n; i += 1024) {
        const int bkt = dbuf[i];
        const int off = rbase[bkt] + (i - loc[bkt]);
        if (off < CAP)                         // memory guard
            binned[bkt * CAP + off] = sbuf[i];
    }
}

// ---------------------------------------------------------------------------
// K2: zp[i][c] = rsqrt(indeg[i]+1) * (x @ W^T)[i][c]  via bf16 MFMA.
//     Block b == bucket b; per-node degree from an LDS histogram of the
//     bucket's binned run (overlaps W staging). (round-10 form, proven)
// ---------------------------------------------------------------------------
__global__ __launch_bounds__(256) void gemm_kernel(const float* __restrict__ x,
                                                   const float* __restrict__ W,
                                                   const int* __restrict__ bcnt,
                                                   const int* __restrict__ binned,
                                                   __half* __restrict__ zp) {
    __shared__ short Wb[64 * 136];
    __shared__ int hcnt[BKT_NODES];
    const int tid  = threadIdx.x;

    if (tid < BKT_NODES) hcnt[tid] = 0;
    __syncthreads();

    // W staging + bucket degree histogram (same phase, independent work)
    const float4* __restrict__ W4 = (const float4*)W;
    for (int idx = tid; idx < 64 * 32; idx += 256) {
        int nn = idx >> 5, k4 = idx & 31;
        float4 v = W4[idx];
        uint2 p;
        p.x = pack2(v.x, v.y);
        p.y = pack2(v.z, v.w);
        *(uint2*)&Wb[nn * 136 + k4 * 4] = p;
    }
    {
        const int n    = min(bcnt[blockIdx.x], CAP);
        const int base = blockIdx.x * CAP;
        for (int i = tid; i < n; i += 256)
            atomicAdd(&hcnt[binned[base + i] & (BKT_NODES - 1)], 1);
    }
    __syncthreads();

    const int lane = tid & 63;
    const int wv   = tid >> 6;
    const int m    = lane & 15;
    const int half = lane >> 4;

    bf16x8 bfr[4][4];
#pragma unroll
    for (int t = 0; t < 4; t++)
#pragma unroll
        for (int j = 0; j < 4; j++)
            bfr[t][j] = *(bf16x8*)&Wb[(j * 16 + m) * 136 + t * 32 + half * 8];

#pragma unroll
    for (int rt = 0; rt < 2; rt++) {
        const int row0 = blockIdx.x * GROWS + rt * 64;
        const int arow = min(row0 + wv * 16 + m, N_NODES - 1);
        const float4* __restrict__ xr = (const float4*)&x[arow * D_FEAT];

        f32x4 acc[4];
#pragma unroll
        for (int j = 0; j < 4; j++) acc[j] = (f32x4){0.f, 0.f, 0.f, 0.f};

#pragma unroll
        for (int t = 0; t < 4; t++) {
            const float4 p0 = xr[t * 8 + half * 2];
            const float4 p1 = xr[t * 8 + half * 2 + 1];
            union { bf16x8 v; unsigned u[4]; } au;
            au.u[0] = pack2(p0.x, p0.y);
            au.u[1] = pack2(p0.z, p0.w);
            au.u[2] = pack2(p1.x, p1.y);
            au.u[3] = pack2(p1.z, p1.w);
#pragma unroll
            for (int j = 0; j < 4; j++)
                acc[j] = __builtin_amdgcn_mfma_f32_16x16x32_bf16(au.v, bfr[t][j], acc[j], 0, 0, 0);
        }

#pragma unroll
        for (int r = 0; r < 4; r++) {
            const int row = row0 + wv * 16 + half * 4 + r;
            if (row < N_NODES) {
                const int nl = rt * 64 + wv * 16 + half * 4 + r;   // 0..127
                const float dinv = rsqrtf((float)(hcnt[nl] + 1));
#pragma unroll
                for (int j = 0; j < 4; j++)
                    zp[row * N_CLASSES + j * 16 + m] = __float2half(acc[j][r] * dinv);
            }
        }
    }
}

// ---------------------------------------------------------------------------
// K3: fused sort + gather-accumulate + epilogue. v5: BLOCK = 512 threads
//     (was 1024). Same 22 KB LDS -> up to 4 blocks/CU (32 waves vs 16):
//     doubles chip-wide outstanding random gathers with ZERO added
//     instructions. Tests the one unprobed axis (TLP) of agg's gather floor.
//     Arithmetic bit-identical to round-8 v4: 8 waves x 2 nodes x 8 passes.
// ---------------------------------------------------------------------------
__global__ __launch_bounds__(512) void agg_kernel(const int* __restrict__ bcnt,
                                                  const int* __restrict__ binned,
                                                  const __half* __restrict__ zp,
                                                  const float* __restrict__ b,
                                                  float* __restrict__ out) {
    __shared__ int buf[CAP];
    __shared__ int sorted[CAP];
    __shared__ int hcnt[BKT_NODES];
    __shared__ int cur[BKT_NODES];
    __shared__ int rowstart[BKT_NODES];

    const int tid  = threadIdx.x;
    const int lane = tid & 63;
    const int wid  = tid >> 6;                 // 0..7

    if (tid < BKT_NODES) { hcnt[tid] = 0; cur[tid] = 0; }
    __syncthreads();

    const int bkt  = blockIdx.x;
    const int n    = min(bcnt[bkt], CAP);
    const int base = bkt * CAP;

    for (int i = tid; i < n; i += 512) {
        int v = binned[base + i];
        buf[i] = v;
        atomicAdd(&hcnt[v & (BKT_NODES - 1)], 1);
    }
    __syncthreads();

    if (wid == 0) {
        int v0 = hcnt[lane];
        int v1 = hcnt[64 + lane];
        int s0 = v0;
#pragma unroll
        for (int off = 1; off < 64; off <<= 1) {
            int t = __shfl_up(s0, off, 64);
            if (lane >= off) s0 += t;
        }
        int tot0 = __shfl(s0, 63, 64);
        int s1 = v1;
#pragma unroll
        for (int off = 1; off < 64; off <<= 1) {
            int t = __shfl_up(s1, off, 64);
            if (lane >= off) s1 += t;
        }
        rowstart[lane]      = s0 - v0;             // exclusive
        rowstart[64 + lane] = s1 + tot0 - v1;
    }
    __syncthreads();

    for (int i = tid; i < n; i += 512) {
        int v  = buf[i];
        int nd = v & (BKT_NODES - 1);
        int p  = atomicAdd(&cur[nd], 1);
        sorted[rowstart[nd] + p] = v >> BKT_SHIFT;
    }
    __syncthreads();

    // gather phase: 8 waves x 2 nodes/wave x 8 passes = 128 nodes
    const int half = lane >> 5;                 // 0 = node A, 1 = node B
    const int sub  = (lane >> 3) & 3;           // edge slot 0..3 within node
    const int o8   = (lane & 7) * 8;            // class octet start

#pragma unroll 1
    for (int pass = 0; pass < 8; pass++) {
        const int nl   = pass * 16 + wid * 2 + half;
        const int node = bkt * BKT_NODES + nl;
        const int cnt  = hcnt[nl];
        const int st   = rowstart[nl];

        float a8[8] = {0.f, 0.f, 0.f, 0.f, 0.f, 0.f, 0.f, 0.f};
        for (int be = 0; be < cnt; be += 64) {
            const int en = min(cnt - be, 64);
            unsigned p2[4] = {0u, 0u, 0u, 0u};
            for (int e = sub; e < en; e += 4) {
                const int row = sorted[st + be + e];
                const u32x4 g = *(const u32x4*)&zp[row * N_CLASSES + o8];
#pragma unroll
                for (int k = 0; k < 4; k++) p2[k] = hadd2u(p2[k], g[k]);
            }
#pragma unroll
            for (int k = 0; k < 4; k++) {
                float2 f = h2f2(p2[k]);
                a8[2 * k]     += f.x;
                a8[2 * k + 1] += f.y;
            }
        }
        // combine 4 edge slots (xor 8,16 — stays within each 32-lane half)
#pragma unroll
        for (int mask = 8; mask <= 16; mask <<= 1)
#pragma unroll
            for (int k = 0; k < 8; k++)
                a8[k] += __shfl_xor(a8[k], mask, 64);

        if (node < N_NODES) {
            // self-loop
            const u32x4 sg = *(const u32x4*)&zp[node * N_CLASSES + o8];
#pragma unroll
            for (int k = 0; k < 4; k++) {
                float2 f = h2f2(sg[k]);
                a8[2 * k]     += f.x;
                a8[2 * k + 1] += f.y;
            }

            const float dinv = rsqrtf((float)(cnt + 1));
            float v[8];
#pragma unroll
            for (int k = 0; k < 8; k++) v[k] = a8[k] * dinv + b[o8 + k];

            float m = v[0];
#pragma unroll
            for (int k = 1; k < 8; k++) m = fmaxf(m, v[k]);
#pragma unroll
            for (int mask = 1; mask <= 4; mask <<= 1)
                m = fmaxf(m, __shfl_xor(m, mask, 64));
            float l = 0.f;
#pragma unroll
            for (int k = 0; k < 8; k++) l += __expf(v[k] - m);
#pragma unroll
            for (int mask = 1; mask <= 4; mask <<= 1)
                l += __shfl_xor(l, mask, 64);
            const float lg = m + __logf(l);

            if (sub == 0) {
                float4 o0, o1;
                o0.x = v[0] - lg; o0.y = v[1] - lg; o0.z = v[2] - lg; o0.w = v[3] - lg;
                o1.x = v[4] - lg; o1.y = v[5] - lg; o1.z = v[6] - lg; o1.w = v[7] - lg;
                *(float4*)&out[node * N_CLASSES + o8]     = o0;
                *(float4*)&out[node * N_CLASSES + o8 + 4] = o1;
            }
        }
    }
}

// ---------------------------------------------------------------------------
// Launch
// ---------------------------------------------------------------------------
extern "C" void kernel_launch(void* const* d_in, const int* in_sizes, int n_in,
                              void* d_out, int out_size, void* d_ws, size_t ws_size,
                              hipStream_t stream) {
    const float* x    = (const float*)d_in[0];
    const int*   edge = (const int*)d_in[1];   // [2,E]: src then dst
    const float* W    = (const float*)d_in[2];
    const float* b    = (const float*)d_in[3];
    float* out = (float*)d_out;

    char* ws = (char*)d_ws;
    int*    bcnt   = (int*)(ws + OFF_BCNT);
    int*    binned = (int*)(ws + OFF_BINNED);
    __half* zp     = (__half*)(ws + OFF_ZP);

    const int* srcv = edge;
    const int* dstv = edge + N_EDGES;

    hipMemsetAsync(bcnt, 0, NB * sizeof(int), stream);
    bin_kernel<<<NBLK_A, 1024, 0, stream>>>(srcv, dstv, bcnt, binned);
    gemm_kernel<<<NBLK_G, 256, 0, stream>>>(x, W, bcnt, binned, zp);
    agg_kernel<<<NB, 512, 0, stream>>>(bcnt, binned, zp, b, out);
}